// Round 18
// baseline (130.325 us; speedup 1.0000x reference)
//
#include <hip/hip_runtime.h>
#include <hip/hip_fp16.h>

// DepthFlowProjection (DAIN, fillhole=0) forward — LDS box-splat scatter.
// R18 = R17 with Sh 20->36 (single change). R17 budget: DS ~84us (2
// lane-RMWs/px: f32 cnt + ds_pk_add_f16 (sx,sy) — minimal while keeping the
// >0 gate exact; tile-size-invariant) + base ~44us (loads/VALU, scales with
// vertical halo amp (Sh+2R)/Sh: 4.2 -> 2.78). LDS 38.2KB keeps 4 blocks/CU;
// grid 1800 % 8 == 0 keeps the XCD swizzle.

constexpr int W  = 1920, H = 1080;
constexpr int HW = W * H;
constexpr int Sh = 36, Wt = 128, R = 32;
constexpr int TX = W / Wt, TY = H / Sh;     // 15, 30
constexpr int SW = Sh * Wt;                 // 4608 outputs per tile
constexpr int SP = (Sh + 1) * (Wt + 1);     // 4773 S-cells per plane (stride 129)
constexpr int SPP = (SP + 3) & ~3;          // padded plane size
constexpr float LEAK_THR = (float)(R - 1);  // 31.0f
constexpr int LEAK_K = 512;                 // records per block segment (mean ~1)
constexpr unsigned HASH_N = 65536;          // corner-fixup hash slots
constexpr unsigned HEMPTY = 0xFFFFFFFFu;

__global__ __launch_bounds__(512, 8) void dfp_tile(
    const float* __restrict__ flow, const float* __restrict__ depth,
    float* __restrict__ cnt_out,        // [B*HW] raw tile cnt plane
    unsigned* __restrict__ leak_counts, // [gridDim.x]
    float4* __restrict__ leak_list,     // [gridDim.x * LEAK_K]
    float* __restrict__ out, int B)
{
    __shared__ __align__(16) float   accF[SPP];   // cnt plane (f32)
    __shared__ __align__(16) __half2 accH[SPP];   // (sx,sy) packed (f16x2)
    __shared__ unsigned s_lcnt;
    const int tid  = threadIdx.x;
    const int lane = tid & 63;
    const int wid  = tid >> 6;

    // XCD-aware swizzle (grid = 1800, mod 8 == 0 -> simple bijective form)
    int nwg  = gridDim.x;
    int orig = blockIdx.x;
    int blk  = ((nwg & 7) == 0) ? (orig & 7) * (nwg >> 3) + (orig >> 3) : orig;

    int b  = blk / (TX * TY);
    int t  = blk - b * (TX * TY);
    int ty = t / TX;
    int tx = t - ty * TX;
    const int Y0 = ty * Sh, X0 = tx * Wt;

    float4* accFv = (float4*)accF;
    float4* accHv = (float4*)accH;
    for (int i = tid; i < SPP / 4; i += 512) {
        accFv[i] = make_float4(0.f, 0.f, 0.f, 0.f);
        accHv[i] = make_float4(0.f, 0.f, 0.f, 0.f);
    }
    if (tid == 0) s_lcnt = 0u;
    __syncthreads();

    const float* fxp = flow + (size_t)b * 2 * HW;
    const float* fyp = fxp + HW;
    const float* dp  = depth + (size_t)b * HW;

    const int r0 = max(Y0 - R, 0), r1 = min(Y0 + Sh + R, H);
    const int c0 = max(X0 - R, 0), c1 = min(X0 + Wt + R, W);
    // region width in {160,192}; chunks 0,1 always full, chunk 2 may be partial
    const int ca  = c0 + lane;            // chunk 0 col (always < c1)
    const int cb  = ca + 64;              // chunk 1 col (always < c1)
    const int ccn = ca + 128;             // chunk 2 nominal col
    const bool okc = ccn < c1;
    const int cc  = okc ? ccn : (c1 - 1); // clamped in-bounds load col

    auto ldrow = [&](int r,
                     float& f0, float& f1, float& f2,
                     float& g0, float& g1, float& g2,
                     float& e0, float& e1, float& e2) {
        size_t rb = (size_t)r * W;
        f0 = fxp[rb + ca]; f1 = fxp[rb + cb]; f2 = fxp[rb + cc];
        g0 = fyp[rb + ca]; g1 = fyp[rb + cb]; g2 = fyp[rb + cc];
        e0 = dp [rb + ca]; e1 = dp [rb + cb]; e2 = dp [rb + cc];
        if (!okc) f2 = 1e30f;   // invalid lanes of chunk 2 -> inert
    };

    auto proc1 = [&](int row, int col, float fx, float fy, float dv) {
        float x2 = (float)col + fx;
        float y2 = (float)row + fy;
        int ixL = (int)floorf(x2);
        int iyT = (int)floorf(y2);
        // ok == valid && !dup  (0 <= ixL < W-1, 0 <= iyT < H-1)
        bool ok = ((unsigned)ixL < (unsigned)(W - 1)) &
                  ((unsigned)iyT < (unsigned)(H - 1));
        bool small = (fabsf(fx) <= LEAK_THR) && (fabsf(fy) <= LEAK_THR);

        if (ok && small) {
            // base-corner accumulate; corners outside our S-window are
            // handled by the neighbor tile (|flow| <= R-1 guarantees it
            // visits this pixel too).
            int a = iyT - Y0 + 1;
            int c = ixL - X0 + 1;
            if ((unsigned)a < (unsigned)(Sh + 1) && (unsigned)c < (unsigned)(Wt + 1)) {
                float vx = -fx * dv, vy = -fy * dv;
                int o = a * (Wt + 1) + c;
                atomicAdd(&accF[o], dv);
                // packed f16x2 LDS atomic add (CDNA ds_pk_add_f16),
                // fire-and-forget (no return -> no wait)
                __half2 hv = __floats2half2_rn(vx, vy);
                unsigned pkb;
                __builtin_memcpy(&pkb, &hv, 4);
                unsigned laddr = (unsigned)(uintptr_t)&accH[o];
                asm volatile("ds_pk_add_f16 %0, %1"
                             :: "v"(laddr), "v"(pkb) : "memory");
            }
        } else if ((unsigned)(row - Y0) < (unsigned)Sh &&
                   (unsigned)(col - X0) < (unsigned)Wt) {
            // rare (big flow or border-dup): append once, by source tile
            bool valid = (x2 >= 0.f) && (y2 >= 0.f) &&
                         (x2 <= (float)(W - 1)) && (y2 <= (float)(H - 1));
            if (valid) {
                float vx = -fx * dv, vy = -fy * dv;
                unsigned idx = atomicAdd(&s_lcnt, 1u);
                if (idx < (unsigned)LEAK_K)
                    leak_list[(size_t)blk * LEAK_K + idx] = make_float4(
                        __int_as_float(b * HW + iyT * W + ixL), dv, vx, vy);
            }
        }
    };

    auto procrow = [&](int row,
                       float f0, float f1, float f2,
                       float g0, float g1, float g2,
                       float e0, float e1, float e2) {
        proc1(row, ca, f0, g0, e0);
        proc1(row, cb, f1, g1, e1);
        proc1(row, ccn, f2, g2, e2);   // invalid lanes carry fx=1e30 -> inert
    };

    // 2-deep software-pipelined row loop; named scalar slots A/B
    int r = r0 + wid;
    float Af0, Af1, Af2, Ag0, Ag1, Ag2, Ae0, Ae1, Ae2;
    float Bf0, Bf1, Bf2, Bg0, Bg1, Bg2, Be0, Be1, Be2;
    if (r     < r1) ldrow(r,     Af0, Af1, Af2, Ag0, Ag1, Ag2, Ae0, Ae1, Ae2);
    if (r + 8 < r1) ldrow(r + 8, Bf0, Bf1, Bf2, Bg0, Bg1, Bg2, Be0, Be1, Be2);
    while (r < r1) {
        if (r + 16 < r1) {
            float t0, t1, t2, t3, t4, t5, t6, t7, t8;
            ldrow(r + 16, t0, t1, t2, t3, t4, t5, t6, t7, t8);
            procrow(r, Af0, Af1, Af2, Ag0, Ag1, Ag2, Ae0, Ae1, Ae2);
            Af0 = t0; Af1 = t1; Af2 = t2;
            Ag0 = t3; Ag1 = t4; Ag2 = t5;
            Ae0 = t6; Ae1 = t7; Ae2 = t8;
        } else {
            procrow(r, Af0, Af1, Af2, Ag0, Ag1, Ag2, Ae0, Ae1, Ae2);
        }
        r += 8;
        if (r >= r1) break;
        if (r + 16 < r1) {
            float t0, t1, t2, t3, t4, t5, t6, t7, t8;
            ldrow(r + 16, t0, t1, t2, t3, t4, t5, t6, t7, t8);
            procrow(r, Bf0, Bf1, Bf2, Bg0, Bg1, Bg2, Be0, Be1, Be2);
            Bf0 = t0; Bf1 = t1; Bf2 = t2;
            Bg0 = t3; Bg1 = t4; Bg2 = t5;
            Be0 = t6; Be1 = t7; Be2 = t8;
        } else {
            procrow(r, Bf0, Bf1, Bf2, Bg0, Bg1, Bg2, Be0, Be1, Be2);
        }
        r += 8;
    }
    __syncthreads();

    if (tid == 0) leak_counts[blk] = min(s_lcnt, (unsigned)LEAK_K);

    // flush: 2x2 window sum of S -> NORMALIZED output (leak pixels fixed up
    // later by dfp_fixup); raw cnt stored for the fixup's denominator.
    float* outx = out + (size_t)b * 2 * HW;
    float* outy = outx + HW;
    for (int i = tid; i < SW; i += 512) {
        int ly = i >> 7;            // Wt = 128
        int lx = i & 127;
        int o  = ly * (Wt + 1) + lx;
        float cnt = accF[o]        + accF[o + 1]
                  + accF[o + Wt+1] + accF[o + Wt+2];
        float2 s00 = __half22float2(accH[o]);
        float2 s01 = __half22float2(accH[o + 1]);
        float2 s10 = __half22float2(accH[o + Wt+1]);
        float2 s11 = __half22float2(accH[o + Wt+2]);
        float sx = s00.x + s01.x + s10.x + s11.x;
        float sy = s00.y + s01.y + s10.y + s11.y;
        float den = (cnt > 0.f) ? cnt : 1.f;
        int gp = (Y0 + ly) * W + (X0 + lx);
        outx[gp] = sx / den;
        outy[gp] = sy / den;
        cnt_out[(size_t)b * HW + gp] = cnt;
    }
}

// Kernel 2: accumulate leak records (4 clamped corners each, reference
// multiplicity) into a small CAS hash. Stream-ordered after dfp_tile.
__global__ void dfp_hash_apply(const float4* __restrict__ list,
                               const unsigned* __restrict__ counts,
                               unsigned* __restrict__ hkey,
                               float* __restrict__ hcnt,
                               float* __restrict__ hsx,
                               float* __restrict__ hsy)
{
    int blk = blockIdx.x;
    unsigned n = counts[blk];
    if (n > (unsigned)LEAK_K) n = LEAK_K;
    const float4* seg = list + (size_t)blk * LEAK_K;
    for (unsigned i = threadIdx.x; i < n; i += blockDim.x) {
        float4 rec = seg[i];
        int pos = __float_as_int(rec.x);
        int bb  = pos / HW;
        int p   = pos - bb * HW;
        int iyT = p / W;
        int ixL = p - iyT * W;
        int ixR = min(ixL + 1, W - 1);
        int iyB = min(iyT + 1, H - 1);
        int base = bb * HW;
        int corners[4] = { base + iyT * W + ixL, base + iyT * W + ixR,
                           base + iyB * W + ixL, base + iyB * W + ixR };
        for (int k = 0; k < 4; ++k) {
            unsigned key = (unsigned)corners[k];
            unsigned h = (key * 2654435761u) >> 16;
            for (unsigned probe = 0; probe < HASH_N; ++probe) {
                unsigned slot = (h + probe) & (HASH_N - 1);
                unsigned old = atomicCAS(&hkey[slot], HEMPTY, key);
                if (old == HEMPTY || old == key) {
                    atomicAdd(&hcnt[slot], rec.y);
                    atomicAdd(&hsx[slot],  rec.z);
                    atomicAdd(&hsy[slot],  rec.w);
                    break;
                }
            }
        }
    }
}

// Kernel 3: sparse fixup of leak-affected pixels. One slot -> one pixel,
// single writer. Reconstruct raw sums from normalized out and raw cnt.
__global__ void dfp_fixup(const unsigned* __restrict__ hkey,
                          const float* __restrict__ hcnt,
                          const float* __restrict__ hsx,
                          const float* __restrict__ hsy,
                          const float* __restrict__ cnt_plane,
                          float* __restrict__ out)
{
    unsigned i = blockIdx.x * blockDim.x + threadIdx.x;
    if (i >= HASH_N) return;
    unsigned key = hkey[i];
    if (key == HEMPTY) return;
    int bb = (int)(key / (unsigned)HW);
    int p  = (int)(key - (unsigned)bb * (unsigned)HW);

    float cnt_t = cnt_plane[key];
    float den_t = (cnt_t > 0.f) ? cnt_t : 1.f;
    size_t o = (size_t)bb * 2 * HW + p;
    float raw_x = out[o]      * den_t + hsx[i];
    float raw_y = out[o + HW] * den_t + hsy[i];
    float cnt_n = cnt_t + hcnt[i];
    float den_n = (cnt_n > 0.f) ? cnt_n : 1.f;
    out[o]      = raw_x / den_n;
    out[o + HW] = raw_y / den_n;
}

// ---------------- fallback (round-1) path if ws is too small ----------------

__global__ void dfp_scatter(const float* __restrict__ flow,
                            const float* __restrict__ depth,
                            float* __restrict__ out,
                            float* __restrict__ count, int B)
{
    const long total = (long)B * HW;
    long idx = (long)blockIdx.x * blockDim.x + threadIdx.x;
    if (idx >= total) return;
    int b = (int)(idx / HW);
    int p = (int)(idx - (long)b * HW);
    int y = p / W;
    int x = p - y * W;
    const float* f = flow + (size_t)b * 2 * HW;
    float fx = f[p], fy = f[HW + p], d = depth[idx];
    float x2 = (float)x + fx, y2 = (float)y + fy;
    if (!(x2 >= 0.f && y2 >= 0.f && x2 <= (float)(W - 1) && y2 <= (float)(H - 1)))
        return;
    int ixL = min(max((int)floorf(x2), 0), W - 1);
    int iyT = min(max((int)floorf(y2), 0), H - 1);
    int ixR = min(ixL + 1, W - 1), iyB = min(iyT + 1, H - 1);
    float vx = -fx * d, vy = -fy * d;
    float* cnt_b  = count + (size_t)b * HW;
    float* outx_b = out + (size_t)b * 2 * HW;
    float* outy_b = outx_b + HW;
    int o00 = iyT * W + ixL, o01 = iyT * W + ixR;
    int o10 = iyB * W + ixL, o11 = iyB * W + ixR;
    atomicAdd(&cnt_b[o00], d);   atomicAdd(&cnt_b[o01], d);
    atomicAdd(&cnt_b[o10], d);   atomicAdd(&cnt_b[o11], d);
    atomicAdd(&outx_b[o00], vx); atomicAdd(&outx_b[o01], vx);
    atomicAdd(&outx_b[o10], vx); atomicAdd(&outx_b[o11], vx);
    atomicAdd(&outy_b[o00], vy); atomicAdd(&outy_b[o01], vy);
    atomicAdd(&outy_b[o11], vy); atomicAdd(&outy_b[o10], vy);
}

__global__ void dfp_normalize_scalar(float* __restrict__ out,
                                     const float* __restrict__ count, int B)
{
    const long total = (long)B * HW;
    long idx = (long)blockIdx.x * blockDim.x + threadIdx.x;
    if (idx >= total) return;
    int b = (int)(idx / HW);
    int p = (int)(idx - (long)b * HW);
    float c = count[idx];
    float den = (c > 0.f) ? c : 1.f;
    size_t o = (size_t)b * 2 * HW + p;
    out[o]      = out[o] / den;
    out[o + HW] = out[o + HW] / den;
}

extern "C" void kernel_launch(void* const* d_in, const int* in_sizes, int n_in,
                              void* d_out, int out_size, void* d_ws, size_t ws_size,
                              hipStream_t stream) {
    const float* flow  = (const float*)d_in[0];
    const float* depth = (const float*)d_in[1];
    float* out = (float*)d_out;

    const int B = in_sizes[1] / HW;
    const long total = (long)B * HW;
    const int grid = B * TX * TY;

    const size_t plane_bytes  = (size_t)total * sizeof(float);
    const size_t hkey_bytes   = (size_t)HASH_N * sizeof(unsigned);
    const size_t hval_bytes   = (size_t)HASH_N * sizeof(float);
    const size_t counts_bytes = ((size_t)grid * sizeof(unsigned) + 255) & ~(size_t)255;
    const size_t list_bytes   = (size_t)grid * LEAK_K * sizeof(float4);
    const size_t need = plane_bytes + hkey_bytes + 3 * hval_bytes
                      + counts_bytes + list_bytes;

    if (ws_size >= need) {
        char* wp = (char*)d_ws;
        float*    cnt    = (float*)wp;                 wp += plane_bytes;
        unsigned* hkey   = (unsigned*)wp;              wp += hkey_bytes;
        float*    hcnt   = (float*)wp;                 wp += hval_bytes;
        float*    hsx    = (float*)wp;                 wp += hval_bytes;
        float*    hsy    = (float*)wp;                 wp += hval_bytes;
        unsigned* counts = (unsigned*)wp;              wp += counts_bytes;
        float4*   list   = (float4*)wp;

        (void)hipMemsetAsync(hkey, 0xFF, hkey_bytes, stream);    // keys = HEMPTY
        (void)hipMemsetAsync(hcnt, 0, 3 * hval_bytes, stream);   // hcnt,hsx,hsy = 0

        dfp_tile<<<grid, 512, 0, stream>>>(flow, depth, cnt, counts, list, out, B);
        dfp_hash_apply<<<grid, 64, 0, stream>>>(list, counts, hkey, hcnt, hsx, hsy);
        dfp_fixup<<<(HASH_N + 255) / 256, 256, 0, stream>>>(hkey, hcnt, hsx, hsy, cnt, out);
    } else {
        const int threads = 256;
        const int blocks = (int)((total + threads - 1) / threads);
        float* cnt = (float*)d_ws;
        (void)hipMemsetAsync(d_out, 0, (size_t)total * 2 * sizeof(float), stream);
        (void)hipMemsetAsync(d_ws, 0, plane_bytes, stream);
        dfp_scatter<<<blocks, threads, 0, stream>>>(flow, depth, out, cnt, B);
        dfp_normalize_scalar<<<blocks, threads, 0, stream>>>(out, cnt, B);
    }
}

// Round 19
// 125.002 us; speedup vs baseline: 1.0426x; 1.0426x over previous
//
#include <hip/hip_runtime.h>
#include <hip/hip_fp16.h>

// DepthFlowProjection (DAIN, fillhole=0) forward — LDS box-splat scatter.
// FINAL (= R17, measured 125.4us total / 128us tile; R18's Sh=36 regressed).
//
// Structure: per-tile (20x128) LDS accumulation of the box-splat identity
// (all 4 corners get the SAME (d,vx,vy) -> accumulate base corner only,
// output = 2x2 window sum). Per valid pixel: 2 LDS lane-RMWs — f32 cnt
// (exact >0 gate) + ds_pk_add_f16 packed (sx,sy). Rare pixels (|flow|>31
// or exact border landing) -> per-block segment append (LDS counter, no
// convergent ops, execz-skippable) -> CAS-hash -> sparse fixup.
// Normalization folded into the tile flush.
//
// Session lessons baked in: global f32 atomics ~25 G/s (R1/2); convergent
// ballot/returned-global-atomic in inner loop linearizes exec (R10-R12);
// DS time scales with lane-RMW count, not instr count/banks (R12-R17);
// runtime-indexed arrays spill (R10).

constexpr int W  = 1920, H = 1080;
constexpr int HW = W * H;
constexpr int Sh = 20, Wt = 128, R = 32;
constexpr int TX = W / Wt, TY = H / Sh;     // 15, 54
constexpr int SW = Sh * Wt;                 // 2560 outputs per tile
constexpr int SP = (Sh + 1) * (Wt + 1);     // 2709 S-cells per plane (stride 129)
constexpr int SPP = (SP + 3) & ~3;          // padded plane size
constexpr float LEAK_THR = (float)(R - 1);  // 31.0f
constexpr int LEAK_K = 512;                 // records per block segment
constexpr unsigned HASH_N = 65536;          // corner-fixup hash slots
constexpr unsigned HEMPTY = 0xFFFFFFFFu;

__global__ __launch_bounds__(512, 8) void dfp_tile(
    const float* __restrict__ flow, const float* __restrict__ depth,
    float* __restrict__ cnt_out,        // [B*HW] raw tile cnt plane
    unsigned* __restrict__ leak_counts, // [gridDim.x]
    float4* __restrict__ leak_list,     // [gridDim.x * LEAK_K]
    float* __restrict__ out, int B)
{
    __shared__ __align__(16) float   accF[SPP];   // cnt plane (f32)
    __shared__ __align__(16) __half2 accH[SPP];   // (sx,sy) packed (f16x2)
    __shared__ unsigned s_lcnt;
    const int tid  = threadIdx.x;
    const int lane = tid & 63;
    const int wid  = tid >> 6;

    // XCD-aware swizzle (grid = 3240, mod 8 == 0 -> simple bijective form)
    int nwg  = gridDim.x;
    int orig = blockIdx.x;
    int blk  = ((nwg & 7) == 0) ? (orig & 7) * (nwg >> 3) + (orig >> 3) : orig;

    int b  = blk / (TX * TY);
    int t  = blk - b * (TX * TY);
    int ty = t / TX;
    int tx = t - ty * TX;
    const int Y0 = ty * Sh, X0 = tx * Wt;

    float4* accFv = (float4*)accF;
    float4* accHv = (float4*)accH;
    for (int i = tid; i < SPP / 4; i += 512) {
        accFv[i] = make_float4(0.f, 0.f, 0.f, 0.f);
        accHv[i] = make_float4(0.f, 0.f, 0.f, 0.f);
    }
    if (tid == 0) s_lcnt = 0u;
    __syncthreads();

    const float* fxp = flow + (size_t)b * 2 * HW;
    const float* fyp = fxp + HW;
    const float* dp  = depth + (size_t)b * HW;

    const int r0 = max(Y0 - R, 0), r1 = min(Y0 + Sh + R, H);
    const int c0 = max(X0 - R, 0), c1 = min(X0 + Wt + R, W);
    // region width in {160,192}; chunks 0,1 always full, chunk 2 may be partial
    const int ca  = c0 + lane;            // chunk 0 col (always < c1)
    const int cb  = ca + 64;              // chunk 1 col (always < c1)
    const int ccn = ca + 128;             // chunk 2 nominal col
    const bool okc = ccn < c1;
    const int cc  = okc ? ccn : (c1 - 1); // clamped in-bounds load col

    auto ldrow = [&](int r,
                     float& f0, float& f1, float& f2,
                     float& g0, float& g1, float& g2,
                     float& e0, float& e1, float& e2) {
        size_t rb = (size_t)r * W;
        f0 = fxp[rb + ca]; f1 = fxp[rb + cb]; f2 = fxp[rb + cc];
        g0 = fyp[rb + ca]; g1 = fyp[rb + cb]; g2 = fyp[rb + cc];
        e0 = dp [rb + ca]; e1 = dp [rb + cb]; e2 = dp [rb + cc];
        if (!okc) f2 = 1e30f;   // invalid lanes of chunk 2 -> inert
    };

    auto proc1 = [&](int row, int col, float fx, float fy, float dv) {
        float x2 = (float)col + fx;
        float y2 = (float)row + fy;
        int ixL = (int)floorf(x2);
        int iyT = (int)floorf(y2);
        // ok == valid && !dup  (0 <= ixL < W-1, 0 <= iyT < H-1)
        bool ok = ((unsigned)ixL < (unsigned)(W - 1)) &
                  ((unsigned)iyT < (unsigned)(H - 1));
        bool small = (fabsf(fx) <= LEAK_THR) && (fabsf(fy) <= LEAK_THR);

        if (ok && small) {
            // base-corner accumulate; corners outside our S-window are
            // handled by the neighbor tile (|flow| <= R-1 guarantees it
            // visits this pixel too).
            int a = iyT - Y0 + 1;
            int c = ixL - X0 + 1;
            if ((unsigned)a < (unsigned)(Sh + 1) && (unsigned)c < (unsigned)(Wt + 1)) {
                float vx = -fx * dv, vy = -fy * dv;
                int o = a * (Wt + 1) + c;
                atomicAdd(&accF[o], dv);
                // packed f16x2 LDS atomic add (CDNA ds_pk_add_f16),
                // fire-and-forget (no return -> no wait)
                __half2 hv = __floats2half2_rn(vx, vy);
                unsigned pkb;
                __builtin_memcpy(&pkb, &hv, 4);
                unsigned laddr = (unsigned)(uintptr_t)&accH[o];
                asm volatile("ds_pk_add_f16 %0, %1"
                             :: "v"(laddr), "v"(pkb) : "memory");
            }
        } else if ((unsigned)(row - Y0) < (unsigned)Sh &&
                   (unsigned)(col - X0) < (unsigned)Wt) {
            // rare (big flow or border-dup): append once, by source tile
            bool valid = (x2 >= 0.f) && (y2 >= 0.f) &&
                         (x2 <= (float)(W - 1)) && (y2 <= (float)(H - 1));
            if (valid) {
                float vx = -fx * dv, vy = -fy * dv;
                unsigned idx = atomicAdd(&s_lcnt, 1u);
                if (idx < (unsigned)LEAK_K)
                    leak_list[(size_t)blk * LEAK_K + idx] = make_float4(
                        __int_as_float(b * HW + iyT * W + ixL), dv, vx, vy);
            }
        }
    };

    auto procrow = [&](int row,
                       float f0, float f1, float f2,
                       float g0, float g1, float g2,
                       float e0, float e1, float e2) {
        proc1(row, ca, f0, g0, e0);
        proc1(row, cb, f1, g1, e1);
        proc1(row, ccn, f2, g2, e2);   // invalid lanes carry fx=1e30 -> inert
    };

    // 2-deep software-pipelined row loop; named scalar slots A/B
    int r = r0 + wid;
    float Af0, Af1, Af2, Ag0, Ag1, Ag2, Ae0, Ae1, Ae2;
    float Bf0, Bf1, Bf2, Bg0, Bg1, Bg2, Be0, Be1, Be2;
    if (r     < r1) ldrow(r,     Af0, Af1, Af2, Ag0, Ag1, Ag2, Ae0, Ae1, Ae2);
    if (r + 8 < r1) ldrow(r + 8, Bf0, Bf1, Bf2, Bg0, Bg1, Bg2, Be0, Be1, Be2);
    while (r < r1) {
        if (r + 16 < r1) {
            float t0, t1, t2, t3, t4, t5, t6, t7, t8;
            ldrow(r + 16, t0, t1, t2, t3, t4, t5, t6, t7, t8);
            procrow(r, Af0, Af1, Af2, Ag0, Ag1, Ag2, Ae0, Ae1, Ae2);
            Af0 = t0; Af1 = t1; Af2 = t2;
            Ag0 = t3; Ag1 = t4; Ag2 = t5;
            Ae0 = t6; Ae1 = t7; Ae2 = t8;
        } else {
            procrow(r, Af0, Af1, Af2, Ag0, Ag1, Ag2, Ae0, Ae1, Ae2);
        }
        r += 8;
        if (r >= r1) break;
        if (r + 16 < r1) {
            float t0, t1, t2, t3, t4, t5, t6, t7, t8;
            ldrow(r + 16, t0, t1, t2, t3, t4, t5, t6, t7, t8);
            procrow(r, Bf0, Bf1, Bf2, Bg0, Bg1, Bg2, Be0, Be1, Be2);
            Bf0 = t0; Bf1 = t1; Bf2 = t2;
            Bg0 = t3; Bg1 = t4; Bg2 = t5;
            Be0 = t6; Be1 = t7; Be2 = t8;
        } else {
            procrow(r, Bf0, Bf1, Bf2, Bg0, Bg1, Bg2, Be0, Be1, Be2);
        }
        r += 8;
    }
    __syncthreads();

    if (tid == 0) leak_counts[blk] = min(s_lcnt, (unsigned)LEAK_K);

    // flush: 2x2 window sum of S -> NORMALIZED output (leak pixels fixed up
    // later by dfp_fixup); raw cnt stored for the fixup's denominator.
    float* outx = out + (size_t)b * 2 * HW;
    float* outy = outx + HW;
    for (int i = tid; i < SW; i += 512) {
        int ly = i >> 7;            // Wt = 128
        int lx = i & 127;
        int o  = ly * (Wt + 1) + lx;
        float cnt = accF[o]        + accF[o + 1]
                  + accF[o + Wt+1] + accF[o + Wt+2];
        float2 s00 = __half22float2(accH[o]);
        float2 s01 = __half22float2(accH[o + 1]);
        float2 s10 = __half22float2(accH[o + Wt+1]);
        float2 s11 = __half22float2(accH[o + Wt+2]);
        float sx = s00.x + s01.x + s10.x + s11.x;
        float sy = s00.y + s01.y + s10.y + s11.y;
        float den = (cnt > 0.f) ? cnt : 1.f;
        int gp = (Y0 + ly) * W + (X0 + lx);
        outx[gp] = sx / den;
        outy[gp] = sy / den;
        cnt_out[(size_t)b * HW + gp] = cnt;
    }
}

// Kernel 2: accumulate leak records (4 clamped corners each, reference
// multiplicity) into a small CAS hash. Stream-ordered after dfp_tile.
__global__ void dfp_hash_apply(const float4* __restrict__ list,
                               const unsigned* __restrict__ counts,
                               unsigned* __restrict__ hkey,
                               float* __restrict__ hcnt,
                               float* __restrict__ hsx,
                               float* __restrict__ hsy)
{
    int blk = blockIdx.x;
    unsigned n = counts[blk];
    if (n > (unsigned)LEAK_K) n = LEAK_K;
    const float4* seg = list + (size_t)blk * LEAK_K;
    for (unsigned i = threadIdx.x; i < n; i += blockDim.x) {
        float4 rec = seg[i];
        int pos = __float_as_int(rec.x);
        int bb  = pos / HW;
        int p   = pos - bb * HW;
        int iyT = p / W;
        int ixL = p - iyT * W;
        int ixR = min(ixL + 1, W - 1);
        int iyB = min(iyT + 1, H - 1);
        int base = bb * HW;
        int corners[4] = { base + iyT * W + ixL, base + iyT * W + ixR,
                           base + iyB * W + ixL, base + iyB * W + ixR };
        for (int k = 0; k < 4; ++k) {
            unsigned key = (unsigned)corners[k];
            unsigned h = (key * 2654435761u) >> 16;
            for (unsigned probe = 0; probe < HASH_N; ++probe) {
                unsigned slot = (h + probe) & (HASH_N - 1);
                unsigned old = atomicCAS(&hkey[slot], HEMPTY, key);
                if (old == HEMPTY || old == key) {
                    atomicAdd(&hcnt[slot], rec.y);
                    atomicAdd(&hsx[slot],  rec.z);
                    atomicAdd(&hsy[slot],  rec.w);
                    break;
                }
            }
        }
    }
}

// Kernel 3: sparse fixup of leak-affected pixels. One slot -> one pixel,
// single writer. Reconstruct raw sums from normalized out and raw cnt.
__global__ void dfp_fixup(const unsigned* __restrict__ hkey,
                          const float* __restrict__ hcnt,
                          const float* __restrict__ hsx,
                          const float* __restrict__ hsy,
                          const float* __restrict__ cnt_plane,
                          float* __restrict__ out)
{
    unsigned i = blockIdx.x * blockDim.x + threadIdx.x;
    if (i >= HASH_N) return;
    unsigned key = hkey[i];
    if (key == HEMPTY) return;
    int bb = (int)(key / (unsigned)HW);
    int p  = (int)(key - (unsigned)bb * (unsigned)HW);

    float cnt_t = cnt_plane[key];
    float den_t = (cnt_t > 0.f) ? cnt_t : 1.f;
    size_t o = (size_t)bb * 2 * HW + p;
    float raw_x = out[o]      * den_t + hsx[i];
    float raw_y = out[o + HW] * den_t + hsy[i];
    float cnt_n = cnt_t + hcnt[i];
    float den_n = (cnt_n > 0.f) ? cnt_n : 1.f;
    out[o]      = raw_x / den_n;
    out[o + HW] = raw_y / den_n;
}

// ---------------- fallback (round-1) path if ws is too small ----------------

__global__ void dfp_scatter(const float* __restrict__ flow,
                            const float* __restrict__ depth,
                            float* __restrict__ out,
                            float* __restrict__ count, int B)
{
    const long total = (long)B * HW;
    long idx = (long)blockIdx.x * blockDim.x + threadIdx.x;
    if (idx >= total) return;
    int b = (int)(idx / HW);
    int p = (int)(idx - (long)b * HW);
    int y = p / W;
    int x = p - y * W;
    const float* f = flow + (size_t)b * 2 * HW;
    float fx = f[p], fy = f[HW + p], d = depth[idx];
    float x2 = (float)x + fx, y2 = (float)y + fy;
    if (!(x2 >= 0.f && y2 >= 0.f && x2 <= (float)(W - 1) && y2 <= (float)(H - 1)))
        return;
    int ixL = min(max((int)floorf(x2), 0), W - 1);
    int iyT = min(max((int)floorf(y2), 0), H - 1);
    int ixR = min(ixL + 1, W - 1), iyB = min(iyT + 1, H - 1);
    float vx = -fx * d, vy = -fy * d;
    float* cnt_b  = count + (size_t)b * HW;
    float* outx_b = out + (size_t)b * 2 * HW;
    float* outy_b = outx_b + HW;
    int o00 = iyT * W + ixL, o01 = iyT * W + ixR;
    int o10 = iyB * W + ixL, o11 = iyB * W + ixR;
    atomicAdd(&cnt_b[o00], d);   atomicAdd(&cnt_b[o01], d);
    atomicAdd(&cnt_b[o10], d);   atomicAdd(&cnt_b[o11], d);
    atomicAdd(&outx_b[o00], vx); atomicAdd(&outx_b[o01], vx);
    atomicAdd(&outx_b[o10], vx); atomicAdd(&outx_b[o11], vx);
    atomicAdd(&outy_b[o00], vy); atomicAdd(&outy_b[o01], vy);
    atomicAdd(&outy_b[o10], vy); atomicAdd(&outy_b[o11], vy);
}

__global__ void dfp_normalize_scalar(float* __restrict__ out,
                                     const float* __restrict__ count, int B)
{
    const long total = (long)B * HW;
    long idx = (long)blockIdx.x * blockDim.x + threadIdx.x;
    if (idx >= total) return;
    int b = (int)(idx / HW);
    int p = (int)(idx - (long)b * HW);
    float c = count[idx];
    float den = (c > 0.f) ? c : 1.f;
    size_t o = (size_t)b * 2 * HW + p;
    out[o]      = out[o] / den;
    out[o + HW] = out[o + HW] / den;
}

extern "C" void kernel_launch(void* const* d_in, const int* in_sizes, int n_in,
                              void* d_out, int out_size, void* d_ws, size_t ws_size,
                              hipStream_t stream) {
    const float* flow  = (const float*)d_in[0];
    const float* depth = (const float*)d_in[1];
    float* out = (float*)d_out;

    const int B = in_sizes[1] / HW;
    const long total = (long)B * HW;
    const int grid = B * TX * TY;

    const size_t plane_bytes  = (size_t)total * sizeof(float);
    const size_t hkey_bytes   = (size_t)HASH_N * sizeof(unsigned);
    const size_t hval_bytes   = (size_t)HASH_N * sizeof(float);
    const size_t counts_bytes = ((size_t)grid * sizeof(unsigned) + 255) & ~(size_t)255;
    const size_t list_bytes   = (size_t)grid * LEAK_K * sizeof(float4);
    const size_t need = plane_bytes + hkey_bytes + 3 * hval_bytes
                      + counts_bytes + list_bytes;

    if (ws_size >= need) {
        char* wp = (char*)d_ws;
        float*    cnt    = (float*)wp;                 wp += plane_bytes;
        unsigned* hkey   = (unsigned*)wp;              wp += hkey_bytes;
        float*    hcnt   = (float*)wp;                 wp += hval_bytes;
        float*    hsx    = (float*)wp;                 wp += hval_bytes;
        float*    hsy    = (float*)wp;                 wp += hval_bytes;
        unsigned* counts = (unsigned*)wp;              wp += counts_bytes;
        float4*   list   = (float4*)wp;

        (void)hipMemsetAsync(hkey, 0xFF, hkey_bytes, stream);    // keys = HEMPTY
        (void)hipMemsetAsync(hcnt, 0, 3 * hval_bytes, stream);   // hcnt,hsx,hsy = 0

        dfp_tile<<<grid, 512, 0, stream>>>(flow, depth, cnt, counts, list, out, B);
        dfp_hash_apply<<<grid, 64, 0, stream>>>(list, counts, hkey, hcnt, hsx, hsy);
        dfp_fixup<<<(HASH_N + 255) / 256, 256, 0, stream>>>(hkey, hcnt, hsx, hsy, cnt, out);
    } else {
        const int threads = 256;
        const int blocks = (int)((total + threads - 1) / threads);
        float* cnt = (float*)d_ws;
        (void)hipMemsetAsync(d_out, 0, (size_t)total * 2 * sizeof(float), stream);
        (void)hipMemsetAsync(d_ws, 0, plane_bytes, stream);
        dfp_scatter<<<blocks, threads, 0, stream>>>(flow, depth, out, cnt, B);
        dfp_normalize_scalar<<<blocks, threads, 0, stream>>>(out, cnt, B);
    }
}